// Round 15
// baseline (1053.661 us; speedup 1.0000x reference)
//
#include <hip/hip_runtime.h>
#include <cmath>

#define SCALE 0.125f

using f32x4  = __attribute__((ext_vector_type(4))) float;
using bf16x8 = __attribute__((ext_vector_type(8))) short;

#define S_WAITCNT_VMCNT(N) asm volatile("s_waitcnt vmcnt(" #N ")" ::: "memory")

__device__ __forceinline__ short f2bf(float f) {
  union { float f; unsigned u; } x; x.f = f;
  return (short)((x.u + 0x7fffu + ((x.u >> 16) & 1u)) >> 16);
}

// pack two f32 -> two bf16 in one u32 (no builtin on gfx950; T12 recipe)
__device__ __forceinline__ unsigned cvt_pk_bf16(float lo, float hi) {
  unsigned r;
  asm volatile("v_cvt_pk_bf16_f32 %0, %1, %2" : "=v"(r) : "v"(lo), "v"(hi));
  return r;
}

// async global->LDS, 16B per lane; dest = wave-uniform base + lane*16
__device__ __forceinline__ void gl_lds16(const void* g, void* l) {
  __builtin_amdgcn_global_load_lds(
      (const __attribute__((address_space(1))) void*)(uintptr_t)g,
      (__attribute__((address_space(3))) void*)(uintptr_t)l,
      16, 0, 0);
}

// ---------- weight transpose+cast: src [L][K][N] f32 -> dst [L][N][K] bf16 ----------
__global__ __launch_bounds__(256) void wtrans_k(const float* __restrict__ src,
                                                short* __restrict__ dst,
                                                int K, int N)
{
  __shared__ float tile[32][33];
  const size_t base = (size_t)blockIdx.z * K * N;
  const int n0 = blockIdx.x * 32, k0 = blockIdx.y * 32;
  const int tx = threadIdx.x, ty = threadIdx.y;   // (32,8)
#pragma unroll
  for (int i = 0; i < 4; ++i)
    tile[ty + 8*i][tx] = src[base + (size_t)(k0 + ty + 8*i)*N + n0 + tx];
  __syncthreads();
#pragma unroll
  for (int i = 0; i < 4; ++i)
    dst[base + (size_t)(n0 + ty + 8*i)*K + k0 + tx] = f2bf(tile[tx][ty + 8*i]);
}

// ---------- LayerNorm over 768; 1 wave per row ----------
// FUSE0: in = x_in + pos (broadcast over batch); also writes xout (f32 residual base)
// OUT_F32: write f32 (final LN to d_out), else bf16
template<int OUT_F32, int FUSE0>
__global__ __launch_bounds__(256)
void ln_k(const float* __restrict__ x, const float* __restrict__ pos,
          const float* __restrict__ w, const float* __restrict__ bb,
          void* __restrict__ out, float* __restrict__ xout)
{
  const int row  = blockIdx.x*4 + (threadIdx.x >> 6);
  const int lane = threadIdx.x & 63;
  const float* xr = x + (size_t)row*768;
  float4 v[3];
  float s = 0.f, s2 = 0.f;
#pragma unroll
  for (int i = 0; i < 3; ++i) {
    const int c = i*256 + lane*4;
    v[i] = *(const float4*)(xr + c);
    if constexpr (FUSE0) {
      const float4 p = *(const float4*)(pos + (size_t)(row & 1023)*768 + c);
      v[i].x += p.x; v[i].y += p.y; v[i].z += p.z; v[i].w += p.w;
      *(float4*)(xout + (size_t)row*768 + c) = v[i];
    }
    s  += v[i].x + v[i].y + v[i].z + v[i].w;
    s2 += v[i].x*v[i].x + v[i].y*v[i].y + v[i].z*v[i].z + v[i].w*v[i].w;
  }
#pragma unroll
  for (int off = 1; off < 64; off <<= 1) {
    s  += __shfl_xor(s,  off);
    s2 += __shfl_xor(s2, off);
  }
  const float mu  = s * (1.0f/768.0f);
  const float inv = rsqrtf(s2*(1.0f/768.0f) - mu*mu + 1e-5f);
#pragma unroll
  for (int i = 0; i < 3; ++i) {
    const int c = i*256 + lane*4;
    const float4 wv = *(const float4*)(w  + c);
    const float4 bv = *(const float4*)(bb + c);
    const float o0 = (v[i].x - mu)*inv*wv.x + bv.x;
    const float o1 = (v[i].y - mu)*inv*wv.y + bv.y;
    const float o2 = (v[i].z - mu)*inv*wv.z + bv.z;
    const float o3 = (v[i].w - mu)*inv*wv.w + bv.w;
    if constexpr (OUT_F32) {
      float4 ov; ov.x=o0; ov.y=o1; ov.z=o2; ov.w=o3;
      *(float4*)((float*)out + (size_t)row*768 + c) = ov;
    } else {
      short4 ov; ov.x=f2bf(o0); ov.y=f2bf(o1); ov.z=f2bf(o2); ov.w=f2bf(o3);
      *(short4*)((short*)out + (size_t)row*768 + c) = ov;
    }
  }
}

// ---------- GEMM: C[M][N] = A[M][K](bf16) * Bt[N][K](bf16)^T ----------
// global_load_lds staging, both-sides XOR swizzle (chunk ^= row&7), 128xBN tile.
// XCD-chunked block swizzle (T1). KS>1: split-K w/ f32 atomics (bias on slice 0).
// DB=1 (T4 counted-vmcnt pipeline; proven at BN=64/48KB = 3 blocks/CU; regresses
// at BN=128/64KB = 2 blocks/CU, measured R11; BN=64 on wide-N shapes regresses
// on arithmetic-intensity, measured R13):
//   stage(kt+1) ; s_waitcnt vmcnt(6) ; s_barrier ; compute(kt) ; s_barrier
// EPI 0: out bf16 = acc ; EPI 1: out bf16 = gelu(acc+bias) ; EPI 2: xio(f32) += acc+bias
template<int EPI, int BN, int KS = 1, int DB = 0>
__global__ __launch_bounds__(256, 2)
void gemm_bt(const short* __restrict__ A, const short* __restrict__ Bt,
             int M, int N, int K,
             short* __restrict__ outB, float* __restrict__ xio,
             const float* __restrict__ bias, short* __restrict__ vt)
{
  constexpr int NI = BN / 32;                   // N frags per wave
  constexpr int NB = DB ? 2 : 1;
  __shared__ __align__(16) short As[NB][128][64];
  __shared__ __align__(16) short Bs[NB][BN][64];
  const int t    = threadIdx.x;
  const int lane = t & 63;
  const int g    = lane >> 4, r15 = lane & 15;
  const int w    = t >> 6;
  const int wm   = w >> 1, wn = w & 1;          // 2x2 waves
  // XCD swizzle: hw-linear bid -> contiguous chunk per XCD (nwg % 8 == 0 always here)
  const int nx  = gridDim.x;
  const int bid = blockIdx.y*nx + blockIdx.x;
  const int cpx = (nx * gridDim.y) >> 3;
  const int nb  = (bid & 7)*cpx + (bid >> 3);
  const int row0 = (nb / nx) * 128;
  const int col0 = (nb % nx) * BN;
  const int kz   = (KS > 1) ? blockIdx.z : 0;
  const int kzo  = kz * (K / KS);               // this slice's k-offset
  const int srow   = lane >> 3;                 // 0..7 (row within 8-row call)
  const int schunk = (lane & 7) ^ srow;         // pre-swizzled source chunk
  f32x4 acc[4][NI] = {};
  const int nk = (K / KS) >> 6;
  auto stageT = [&](int buf, int kt) {
    const int k0 = kzo + (kt << 6);
#pragma unroll
    for (int i = 0; i < 4; ++i) {               // A: wave w stages rows [w*32, w*32+32)
      const int r = w*32 + i*8;
      gl_lds16(A + (size_t)(row0 + r + srow)*K + k0 + schunk*8, &As[buf][r][0]);
    }
#pragma unroll
    for (int i = 0; i < BN/32; ++i) {           // B: wave w stages rows [w*BN/4, ...)
      const int r = w*(BN/4) + i*8;
      gl_lds16(Bt + (size_t)(col0 + r + srow)*K + k0 + schunk*8, &Bs[buf][r][0]);
    }
  };
  auto computeT = [&](int buf) {
#pragma unroll
    for (int kk = 0; kk < 2; ++kk) {
      bf16x8 af[4], bfr[NI];
#pragma unroll
      for (int mi = 0; mi < 4; ++mi) {
        const int r = wm*64 + mi*16 + r15;
        const int c = (kk*4 + g) ^ (r & 7);     // swizzled read
        af[mi] = *(const bf16x8*)(&As[buf][r][c*8]);
      }
#pragma unroll
      for (int ni = 0; ni < NI; ++ni) {
        const int r = wn*(BN/2) + ni*16 + r15;
        const int c = (kk*4 + g) ^ (r & 7);
        bfr[ni] = *(const bf16x8*)(&Bs[buf][r][c*8]);
      }
#pragma unroll
      for (int mi = 0; mi < 4; ++mi)
#pragma unroll
        for (int ni = 0; ni < NI; ++ni)
          acc[mi][ni] = __builtin_amdgcn_mfma_f32_16x16x32_bf16(af[mi], bfr[ni], acc[mi][ni], 0, 0, 0);
    }
  };
  if constexpr (DB) {
    stageT(0, 0);
    for (int kt = 0; kt < nk; ++kt) {
      const int cur = kt & 1;
      __builtin_amdgcn_sched_barrier(0);
      if (kt + 1 < nk) {
        stageT(cur ^ 1, kt + 1);                // prefetch: stays in flight over barrier
        if constexpr (BN == 64) S_WAITCNT_VMCNT(6); else S_WAITCNT_VMCNT(8);
      } else {
        S_WAITCNT_VMCNT(0);
      }
      __builtin_amdgcn_sched_barrier(0);
      __builtin_amdgcn_s_barrier();             // all waves' stage(kt) landed
      __builtin_amdgcn_sched_barrier(0);
      computeT(cur);
      __builtin_amdgcn_sched_barrier(0);
      __builtin_amdgcn_s_barrier();             // buf kt&1 free for reuse
    }
  } else {
    for (int kt = 0; kt < nk; ++kt) {
      stageT(0, kt);
      __syncthreads();
      computeT(0);
      __syncthreads();
    }
  }
#pragma unroll
  for (int mi = 0; mi < 4; ++mi)
#pragma unroll
    for (int ni = 0; ni < NI; ++ni) {
      const int rr0 = row0 + wm*64 + mi*16 + g*4;        // C/D: col=lane&15, row=(lane>>4)*4+reg
      const int cc  = col0 + wn*(BN/2) + ni*16 + r15;
#pragma unroll
      for (int reg = 0; reg < 4; ++reg) {
        const float v = acc[mi][ni][reg];
        if constexpr (EPI == 0) {
          outB[(size_t)(rr0 + reg)*N + cc] = f2bf(v);
        } else if constexpr (EPI == 1) {
          const float u = v + bias[cc];
          outB[(size_t)(rr0 + reg)*N + cc] = f2bf(0.5f*u*(1.0f + erff(u*0.70710678f)));
        } else {
          const size_t o = (size_t)(rr0 + reg)*N + cc;
          if constexpr (KS == 1) {
            xio[o] += v + bias[cc];
          } else {
            unsafeAtomicAdd(&xio[o], v + (kz == 0 ? bias[cc] : 0.0f));
          }
        }
      }
      if constexpr (EPI == 0) {
        if (vt != nullptr && cc >= 1536) {               // fused V transpose
          const int hd = cc - 1536;                      // h*64 + d
          const int bb = rr0 >> 10, s = rr0 & 1023;
          short4 o;
          o.x = f2bf(acc[mi][ni][0]); o.y = f2bf(acc[mi][ni][1]);
          o.z = f2bf(acc[mi][ni][2]); o.w = f2bf(acc[mi][ni][3]);
          *(short4*)(vt + (((size_t)bb*768 + hd) << 10) + s) = o;
        }
      }
    }
}

// ---------- block-causal flash attention, LDS-staged K/V + swapped-QK^T ----------
// One block per (qf,h,b). Per step (64 tokens = 1 frame): the block cooperatively
// stages NEXT frame's K and V into LDS[buf^1] (global_load_lds, async, linear dest
// + pre-swizzled source chunk c^(row&7)), computes on LDS[buf]. One __syncthreads
// per step (its vmcnt drain lands AFTER compute -> staging overlaps compute).
// Swapped mfma(K,Q): lane owns one q-row -> scalar softmax, O^T epilogue free.
__global__ __launch_bounds__(256, 2)
void attn_k(const short* __restrict__ qkv, const short* __restrict__ vt,
            short* __restrict__ aout)
{
  const int qf = (blockIdx.x*5 + blockIdx.y) & 15;   // bijective scramble vs CU assignment
  const int h = blockIdx.y, b = blockIdx.z;
  const int t = threadIdx.x, w = t >> 6, lane = t & 63;
  const int g = lane >> 4, r15 = lane & 15;
  __shared__ __align__(16) short Kl[2][64][64];      // [buf][token][d-chunk swz]
  __shared__ __align__(16) short Vl[2][64][64];      // [buf][d][token-chunk swz]
  __shared__ __align__(16) short P_lds[4][16][72];   // per-wave P tile
  short* Prow = &P_lds[w][r15][0];
  const int tok0 = b*1024 + qf*64 + w*16;
  bf16x8 aq[2];
#pragma unroll
  for (int kk = 0; kk < 2; ++kk)
    aq[kk] = *(const bf16x8*)(qkv + (size_t)(tok0 + r15)*2304 + h*64 + kk*32 + g*8);
  const short* kbase = qkv + (size_t)(b*1024)*2304 + 768 + h*64;
  const short* vbase = vt + (size_t)((b*12 + h)*64)*1024;
  const int lr8 = lane >> 3;                         // 0..7: row within 8-row stage
  const int lc  = lane & 7;                          // chunk slot
  // stage frame kf into buffer buf: wave w covers rows [w*16, w*16+16) of K and V
  auto stage = [&](int buf, int kf) {
#pragma unroll
    for (int i = 0; i < 2; ++i) {
      const int r0 = w*16 + i*8;
      const int lr = r0 + lr8;                       // this lane's local row
      const int c  = lc ^ (lr & 7);                  // pre-swizzled source chunk
      gl_lds16(kbase + (size_t)(kf*64 + lr)*2304 + c*8, &Kl[buf][r0][0]);
      gl_lds16(vbase + (size_t)lr*1024 + kf*64 + c*8, &Vl[buf][r0][0]);
    }
  };
  float m = -1e30f, lsum = 0.f;
  f32x4 O[4] = {};
  const int nf = qf + 1;
  stage(0, 0);
  __syncthreads();                                   // drain vmcnt + barrier
  for (int kf = 0; kf < nf; ++kf) {
    const int cur = kf & 1;
    if (kf + 1 < nf) stage(cur ^ 1, kf + 1);         // async prefetch next frame
    // K frags from LDS (swizzled read) + swapped QK^T
    f32x4 s[4];
    __builtin_amdgcn_s_setprio(1);
#pragma unroll
    for (int nj = 0; nj < 4; ++nj) {
      const int tr = nj*16 + r15;
      const bf16x8 k0 = *(const bf16x8*)(&Kl[cur][tr][((0*4 + g) ^ (tr & 7)) * 8]);
      const bf16x8 k1 = *(const bf16x8*)(&Kl[cur][tr][((1*4 + g) ^ (tr & 7)) * 8]);
      f32x4 z = {};
      z     = __builtin_amdgcn_mfma_f32_16x16x32_bf16(k0, aq[0], z, 0, 0, 0);
      s[nj] = __builtin_amdgcn_mfma_f32_16x16x32_bf16(k1, aq[1], z, 0, 0, 0);
    }
    __builtin_amdgcn_s_setprio(0);
    // V frags from LDS (independent of softmax; compiler schedules)
    bf16x8 av[2][4];
#pragma unroll
    for (int kc = 0; kc < 2; ++kc)
#pragma unroll
      for (int di = 0; di < 4; ++di) {
        const int dr = di*16 + r15;
        av[kc][di] = *(const bf16x8*)(&Vl[cur][dr][((kc*4 + g) ^ (dr & 7)) * 8]);
      }
    // scalar softmax: in-lane max over 16, 2 shuffles across the q-group
    float pmax = -1e30f;
#pragma unroll
    for (int nj = 0; nj < 4; ++nj)
      pmax = fmaxf(pmax, fmaxf(fmaxf(s[nj][0], s[nj][1]), fmaxf(s[nj][2], s[nj][3])));
    pmax *= SCALE;
    pmax = fmaxf(pmax, __shfl_xor(pmax, 16));
    pmax = fmaxf(pmax, __shfl_xor(pmax, 32));
    if (!__all(pmax - m <= 8.0f)) {                  // defer-max rescale (THR=8)
      const float mn = fmaxf(m, pmax);
      const float fac = __expf(m - mn);
      m = mn; lsum *= fac;
#pragma unroll
      for (int di = 0; di < 4; ++di) {
        O[di][0] *= fac; O[di][1] *= fac; O[di][2] *= fac; O[di][3] *= fac;
      }
    }
    float rs = 0.f;
    short4 pw[4];
#pragma unroll
    for (int nj = 0; nj < 4; ++nj) {
      const float p0 = __expf(s[nj][0]*SCALE - m);
      const float p1 = __expf(s[nj][1]*SCALE - m);
      const float p2 = __expf(s[nj][2]*SCALE - m);
      const float p3 = __expf(s[nj][3]*SCALE - m);
      rs += (p0 + p1) + (p2 + p3);
      union { unsigned u; short2 s2; } c0, c1;
      c0.u = cvt_pk_bf16(p0, p1);
      c1.u = cvt_pk_bf16(p2, p3);
      pw[nj].x = c0.s2.x; pw[nj].y = c0.s2.y;
      pw[nj].z = c1.s2.x; pw[nj].w = c1.s2.y;
    }
    rs += __shfl_xor(rs, 16);
    rs += __shfl_xor(rs, 32);
    lsum += rs;
    // P roundtrip through per-wave LDS (row q = this lane)
#pragma unroll
    for (int nj = 0; nj < 4; ++nj)
      *(short4*)(Prow + nj*16 + g*4) = pw[nj];
    asm volatile("s_waitcnt lgkmcnt(0)" ::: "memory");  // rule #18 fence
    __builtin_amdgcn_sched_barrier(0);
    __builtin_amdgcn_s_setprio(1);
#pragma unroll
    for (int kc = 0; kc < 2; ++kc) {
      const bf16x8 bp = *(const bf16x8*)(Prow + kc*32 + g*8);
#pragma unroll
      for (int di = 0; di < 4; ++di)
        O[di] = __builtin_amdgcn_mfma_f32_16x16x32_bf16(av[kc][di], bp, O[di], 0, 0, 0);
    }
    __builtin_amdgcn_s_setprio(0);
    __syncthreads();                                 // drains prefetch vmcnt + barrier
  }
  const float invl = 1.0f / lsum;
#pragma unroll
  for (int di = 0; di < 4; ++di) {
    uint2 uv;
    uv.x = cvt_pk_bf16(O[di][0]*invl, O[di][1]*invl);
    uv.y = cvt_pk_bf16(O[di][2]*invl, O[di][3]*invl);
    *(uint2*)(aout + (size_t)(tok0 + r15)*768 + h*64 + di*16 + g*4) = uv;
  }
}

extern "C" void kernel_launch(void* const* d_in, const int* in_sizes, int n_in,
                              void* d_out, int out_size, void* d_ws, size_t ws_size,
                              hipStream_t stream)
{
  (void)in_sizes; (void)n_in; (void)out_size; (void)ws_size;
  const float* x_in = (const float*)d_in[0];
  const float* pos  = (const float*)d_in[1];
  const float* ln1w = (const float*)d_in[2];
  const float* ln1b = (const float*)d_in[3];
  const float* wqkv = (const float*)d_in[4];
  const float* wo   = (const float*)d_in[5];
  const float* bo   = (const float*)d_in[6];
  const float* ln2w = (const float*)d_in[7];
  const float* ln2b = (const float*)d_in[8];
  const float* w1   = (const float*)d_in[9];
  const float* b1   = (const float*)d_in[10];
  const float* w2   = (const float*)d_in[11];
  const float* b2   = (const float*)d_in[12];
  const float* lnfw = (const float*)d_in[13];
  const float* lnfb = (const float*)d_in[14];

  size_t off = 0;
  auto carve = [&](size_t bytes) {
    void* p = (char*)d_ws + off;
    off += (bytes + 255) & ~(size_t)255;
    return p;
  };
  short* wqkvT = (short*)carve((size_t)6*2304*768*2);
  short* woT   = (short*)carve((size_t)6*768*768*2);
  short* w1T   = (short*)carve((size_t)6*3072*768*2);
  short* w2T   = (short*)carve((size_t)6*768*3072*2);
  float* x     = (float*)carve((size_t)4096*768*4);
  short* hbuf  = (short*)carve((size_t)4096*768*2);
  short* qkv   = (short*)carve((size_t)4096*2304*2);
  short* vt    = (short*)carve((size_t)48*64*1024*2);
  short* aout  = (short*)carve((size_t)4096*768*2);
  short* mid   = (short*)carve((size_t)4096*3072*2);

  wtrans_k<<<dim3(72,24,6), dim3(32,8), 0, stream>>>(wqkv, wqkvT, 768, 2304);
  wtrans_k<<<dim3(24,24,6), dim3(32,8), 0, stream>>>(wo,   woT,   768, 768);
  wtrans_k<<<dim3(96,24,6), dim3(32,8), 0, stream>>>(w1,   w1T,   768, 3072);
  wtrans_k<<<dim3(24,96,6), dim3(32,8), 0, stream>>>(w2,   w2T,   3072, 768);

  for (int L = 0; L < 6; ++L) {
    if (L == 0)
      ln_k<0,1><<<1024, 256, 0, stream>>>(x_in, pos, ln1w, ln1b, hbuf, x);
    else
      ln_k<0,0><<<1024, 256, 0, stream>>>(x, nullptr, ln1w + L*768, ln1b + L*768, hbuf, nullptr);
    gemm_bt<0,128,1,0><<<dim3(18,32), 256, 0, stream>>>(hbuf, wqkvT + (size_t)L*2304*768,
                                                        4096, 2304, 768, qkv, nullptr, nullptr, vt);
    attn_k<<<dim3(16,12,4), 256, 0, stream>>>(qkv, vt, aout);
    gemm_bt<2,64,2,1><<<dim3(12,32,2), 256, 0, stream>>>(aout, woT + (size_t)L*768*768,
                                                         4096, 768, 768, nullptr, x, bo + L*768, nullptr);
    ln_k<0,0><<<1024, 256, 0, stream>>>(x, nullptr, ln2w + L*768, ln2b + L*768, hbuf, nullptr);
    gemm_bt<1,128,1,0><<<dim3(24,32), 256, 0, stream>>>(hbuf, w1T + (size_t)L*3072*768,
                                                        4096, 3072, 768, mid, nullptr, b1 + L*3072, nullptr);
    gemm_bt<2,64,4,1><<<dim3(12,32,4), 256, 0, stream>>>(mid, w2T + (size_t)L*768*3072,
                                                         4096, 768, 3072, nullptr, x, b2 + L*768, nullptr);
  }
  ln_k<1,0><<<1024, 256, 0, stream>>>(x, nullptr, lnfw, lnfb, d_out, nullptr);
}

// Round 16
// 950.504 us; speedup vs baseline: 1.1085x; 1.1085x over previous
//
#include <hip/hip_runtime.h>
#include <cmath>

#define SCALE 0.125f

using f32x4  = __attribute__((ext_vector_type(4))) float;
using bf16x8 = __attribute__((ext_vector_type(8))) short;

#define S_WAITCNT_VMCNT(N) asm volatile("s_waitcnt vmcnt(" #N ")" ::: "memory")

__device__ __forceinline__ short f2bf(float f) {
  union { float f; unsigned u; } x; x.f = f;
  return (short)((x.u + 0x7fffu + ((x.u >> 16) & 1u)) >> 16);
}

// pack two f32 -> two bf16 in one u32 (no builtin on gfx950; T12 recipe)
__device__ __forceinline__ unsigned cvt_pk_bf16(float lo, float hi) {
  unsigned r;
  asm volatile("v_cvt_pk_bf16_f32 %0, %1, %2" : "=v"(r) : "v"(lo), "v"(hi));
  return r;
}

// async global->LDS, 16B per lane; dest = wave-uniform base + lane*16
__device__ __forceinline__ void gl_lds16(const void* g, void* l) {
  __builtin_amdgcn_global_load_lds(
      (const __attribute__((address_space(1))) void*)(uintptr_t)g,
      (__attribute__((address_space(3))) void*)(uintptr_t)l,
      16, 0, 0);
}

// ---------- weight transpose+cast: src [L][K][N] f32 -> dst [L][N][K] bf16 ----------
__global__ __launch_bounds__(256) void wtrans_k(const float* __restrict__ src,
                                                short* __restrict__ dst,
                                                int K, int N)
{
  __shared__ float tile[32][33];
  const size_t base = (size_t)blockIdx.z * K * N;
  const int n0 = blockIdx.x * 32, k0 = blockIdx.y * 32;
  const int tx = threadIdx.x, ty = threadIdx.y;   // (32,8)
#pragma unroll
  for (int i = 0; i < 4; ++i)
    tile[ty + 8*i][tx] = src[base + (size_t)(k0 + ty + 8*i)*N + n0 + tx];
  __syncthreads();
#pragma unroll
  for (int i = 0; i < 4; ++i)
    dst[base + (size_t)(n0 + ty + 8*i)*K + k0 + tx] = f2bf(tile[tx][ty + 8*i]);
}

// ---------- LayerNorm over 768; 1 wave per row ----------
// FUSE0: in = x_in + pos (broadcast over batch); also writes xout (f32 residual base)
// OUT_F32: write f32 (final LN to d_out), else bf16
template<int OUT_F32, int FUSE0>
__global__ __launch_bounds__(256)
void ln_k(const float* __restrict__ x, const float* __restrict__ pos,
          const float* __restrict__ w, const float* __restrict__ bb,
          void* __restrict__ out, float* __restrict__ xout)
{
  const int row  = blockIdx.x*4 + (threadIdx.x >> 6);
  const int lane = threadIdx.x & 63;
  const float* xr = x + (size_t)row*768;
  float4 v[3];
  float s = 0.f, s2 = 0.f;
#pragma unroll
  for (int i = 0; i < 3; ++i) {
    const int c = i*256 + lane*4;
    v[i] = *(const float4*)(xr + c);
    if constexpr (FUSE0) {
      const float4 p = *(const float4*)(pos + (size_t)(row & 1023)*768 + c);
      v[i].x += p.x; v[i].y += p.y; v[i].z += p.z; v[i].w += p.w;
      *(float4*)(xout + (size_t)row*768 + c) = v[i];
    }
    s  += v[i].x + v[i].y + v[i].z + v[i].w;
    s2 += v[i].x*v[i].x + v[i].y*v[i].y + v[i].z*v[i].z + v[i].w*v[i].w;
  }
#pragma unroll
  for (int off = 1; off < 64; off <<= 1) {
    s  += __shfl_xor(s,  off);
    s2 += __shfl_xor(s2, off);
  }
  const float mu  = s * (1.0f/768.0f);
  const float inv = rsqrtf(s2*(1.0f/768.0f) - mu*mu + 1e-5f);
#pragma unroll
  for (int i = 0; i < 3; ++i) {
    const int c = i*256 + lane*4;
    const float4 wv = *(const float4*)(w  + c);
    const float4 bv = *(const float4*)(bb + c);
    const float o0 = (v[i].x - mu)*inv*wv.x + bv.x;
    const float o1 = (v[i].y - mu)*inv*wv.y + bv.y;
    const float o2 = (v[i].z - mu)*inv*wv.z + bv.z;
    const float o3 = (v[i].w - mu)*inv*wv.w + bv.w;
    if constexpr (OUT_F32) {
      float4 ov; ov.x=o0; ov.y=o1; ov.z=o2; ov.w=o3;
      *(float4*)((float*)out + (size_t)row*768 + c) = ov;
    } else {
      short4 ov; ov.x=f2bf(o0); ov.y=f2bf(o1); ov.z=f2bf(o2); ov.w=f2bf(o3);
      *(short4*)((short*)out + (size_t)row*768 + c) = ov;
    }
  }
}

// ---------- GEMM: C[M][N] = A[M][K](bf16) * Bt[N][K](bf16)^T ----------
// global_load_lds staging, both-sides XOR swizzle (chunk ^= row&7), 128xBN tile.
// XCD-chunked block swizzle (T1). KS>1: split-K w/ f32 atomics (bias on slice 0).
// Measured config space (R9-R14): BN=64+KS=2+DB=1 proven on wo/w2 (39.3 us);
// BN=128 best at DB=0 (64KB dbuf halves occupancy, R11); BN=64 on wide-N
// regresses (R13); KS=4 atomic-bound (R14). This is the R12-optimal config.
// EPI 0: out bf16 = acc ; EPI 1: out bf16 = gelu(acc+bias) ; EPI 2: xio(f32) += acc+bias
template<int EPI, int BN, int KS = 1, int DB = 0>
__global__ __launch_bounds__(256, 2)
void gemm_bt(const short* __restrict__ A, const short* __restrict__ Bt,
             int M, int N, int K,
             short* __restrict__ outB, float* __restrict__ xio,
             const float* __restrict__ bias, short* __restrict__ vt)
{
  constexpr int NI = BN / 32;                   // N frags per wave
  constexpr int NB = DB ? 2 : 1;
  __shared__ __align__(16) short As[NB][128][64];
  __shared__ __align__(16) short Bs[NB][BN][64];
  const int t    = threadIdx.x;
  const int lane = t & 63;
  const int g    = lane >> 4, r15 = lane & 15;
  const int w    = t >> 6;
  const int wm   = w >> 1, wn = w & 1;          // 2x2 waves
  // XCD swizzle: hw-linear bid -> contiguous chunk per XCD (nwg % 8 == 0 always here)
  const int nx  = gridDim.x;
  const int bid = blockIdx.y*nx + blockIdx.x;
  const int cpx = (nx * gridDim.y) >> 3;
  const int nb  = (bid & 7)*cpx + (bid >> 3);
  const int row0 = (nb / nx) * 128;
  const int col0 = (nb % nx) * BN;
  const int kz   = (KS > 1) ? blockIdx.z : 0;
  const int kzo  = kz * (K / KS);               // this slice's k-offset
  const int srow   = lane >> 3;                 // 0..7 (row within 8-row call)
  const int schunk = (lane & 7) ^ srow;         // pre-swizzled source chunk
  f32x4 acc[4][NI] = {};
  const int nk = (K / KS) >> 6;
  auto stageT = [&](int buf, int kt) {
    const int k0 = kzo + (kt << 6);
#pragma unroll
    for (int i = 0; i < 4; ++i) {               // A: wave w stages rows [w*32, w*32+32)
      const int r = w*32 + i*8;
      gl_lds16(A + (size_t)(row0 + r + srow)*K + k0 + schunk*8, &As[buf][r][0]);
    }
#pragma unroll
    for (int i = 0; i < BN/32; ++i) {           // B: wave w stages rows [w*BN/4, ...)
      const int r = w*(BN/4) + i*8;
      gl_lds16(Bt + (size_t)(col0 + r + srow)*K + k0 + schunk*8, &Bs[buf][r][0]);
    }
  };
  auto computeT = [&](int buf) {
#pragma unroll
    for (int kk = 0; kk < 2; ++kk) {
      bf16x8 af[4], bfr[NI];
#pragma unroll
      for (int mi = 0; mi < 4; ++mi) {
        const int r = wm*64 + mi*16 + r15;
        const int c = (kk*4 + g) ^ (r & 7);     // swizzled read
        af[mi] = *(const bf16x8*)(&As[buf][r][c*8]);
      }
#pragma unroll
      for (int ni = 0; ni < NI; ++ni) {
        const int r = wn*(BN/2) + ni*16 + r15;
        const int c = (kk*4 + g) ^ (r & 7);
        bfr[ni] = *(const bf16x8*)(&Bs[buf][r][c*8]);
      }
#pragma unroll
      for (int mi = 0; mi < 4; ++mi)
#pragma unroll
        for (int ni = 0; ni < NI; ++ni)
          acc[mi][ni] = __builtin_amdgcn_mfma_f32_16x16x32_bf16(af[mi], bfr[ni], acc[mi][ni], 0, 0, 0);
    }
  };
  if constexpr (DB) {
    stageT(0, 0);
    for (int kt = 0; kt < nk; ++kt) {
      const int cur = kt & 1;
      __builtin_amdgcn_sched_barrier(0);
      if (kt + 1 < nk) {
        stageT(cur ^ 1, kt + 1);                // prefetch: stays in flight over barrier
        if constexpr (BN == 64) S_WAITCNT_VMCNT(6); else S_WAITCNT_VMCNT(8);
      } else {
        S_WAITCNT_VMCNT(0);
      }
      __builtin_amdgcn_sched_barrier(0);
      __builtin_amdgcn_s_barrier();             // all waves' stage(kt) landed
      __builtin_amdgcn_sched_barrier(0);
      computeT(cur);
      __builtin_amdgcn_sched_barrier(0);
      __builtin_amdgcn_s_barrier();             // buf kt&1 free for reuse
    }
  } else {
    for (int kt = 0; kt < nk; ++kt) {
      stageT(0, kt);
      __syncthreads();
      computeT(0);
      __syncthreads();
    }
  }
#pragma unroll
  for (int mi = 0; mi < 4; ++mi)
#pragma unroll
    for (int ni = 0; ni < NI; ++ni) {
      const int rr0 = row0 + wm*64 + mi*16 + g*4;        // C/D: col=lane&15, row=(lane>>4)*4+reg
      const int cc  = col0 + wn*(BN/2) + ni*16 + r15;
#pragma unroll
      for (int reg = 0; reg < 4; ++reg) {
        const float v = acc[mi][ni][reg];
        if constexpr (EPI == 0) {
          outB[(size_t)(rr0 + reg)*N + cc] = f2bf(v);
        } else if constexpr (EPI == 1) {
          const float u = v + bias[cc];
          outB[(size_t)(rr0 + reg)*N + cc] = f2bf(0.5f*u*(1.0f + erff(u*0.70710678f)));
        } else {
          const size_t o = (size_t)(rr0 + reg)*N + cc;
          if constexpr (KS == 1) {
            xio[o] += v + bias[cc];
          } else {
            unsafeAtomicAdd(&xio[o], v + (kz == 0 ? bias[cc] : 0.0f));
          }
        }
      }
      if constexpr (EPI == 0) {
        if (vt != nullptr && cc >= 1536) {               // fused V transpose
          const int hd = cc - 1536;                      // h*64 + d
          const int bb = rr0 >> 10, s = rr0 & 1023;
          short4 o;
          o.x = f2bf(acc[mi][ni][0]); o.y = f2bf(acc[mi][ni][1]);
          o.z = f2bf(acc[mi][ni][2]); o.w = f2bf(acc[mi][ni][3]);
          *(short4*)(vt + (((size_t)bb*768 + hd) << 10) + s) = o;
        }
      }
    }
}

// ---------- block-causal flash attention, LDS-staged K/V + swapped-QK^T ----------
// One block per (qf,h,b). Per step (64 tokens = 1 frame): the block cooperatively
// stages NEXT frame's K and V into LDS[buf^1] (global_load_lds, async, linear dest
// + pre-swizzled source chunk c^(row&7)), computes on LDS[buf]. One __syncthreads
// per step (its vmcnt drain lands AFTER compute -> staging overlaps compute).
// Swapped mfma(K,Q): lane owns one q-row -> scalar softmax, O^T epilogue free.
__global__ __launch_bounds__(256, 2)
void attn_k(const short* __restrict__ qkv, const short* __restrict__ vt,
            short* __restrict__ aout)
{
  const int qf = (blockIdx.x*5 + blockIdx.y) & 15;   // bijective scramble vs CU assignment
  const int h = blockIdx.y, b = blockIdx.z;
  const int t = threadIdx.x, w = t >> 6, lane = t & 63;
  const int g = lane >> 4, r15 = lane & 15;
  __shared__ __align__(16) short Kl[2][64][64];      // [buf][token][d-chunk swz]
  __shared__ __align__(16) short Vl[2][64][64];      // [buf][d][token-chunk swz]
  __shared__ __align__(16) short P_lds[4][16][72];   // per-wave P tile
  short* Prow = &P_lds[w][r15][0];
  const int tok0 = b*1024 + qf*64 + w*16;
  bf16x8 aq[2];
#pragma unroll
  for (int kk = 0; kk < 2; ++kk)
    aq[kk] = *(const bf16x8*)(qkv + (size_t)(tok0 + r15)*2304 + h*64 + kk*32 + g*8);
  const short* kbase = qkv + (size_t)(b*1024)*2304 + 768 + h*64;
  const short* vbase = vt + (size_t)((b*12 + h)*64)*1024;
  const int lr8 = lane >> 3;                         // 0..7: row within 8-row stage
  const int lc  = lane & 7;                          // chunk slot
  // stage frame kf into buffer buf: wave w covers rows [w*16, w*16+16) of K and V
  auto stage = [&](int buf, int kf) {
#pragma unroll
    for (int i = 0; i < 2; ++i) {
      const int r0 = w*16 + i*8;
      const int lr = r0 + lr8;                       // this lane's local row
      const int c  = lc ^ (lr & 7);                  // pre-swizzled source chunk
      gl_lds16(kbase + (size_t)(kf*64 + lr)*2304 + c*8, &Kl[buf][r0][0]);
      gl_lds16(vbase + (size_t)lr*1024 + kf*64 + c*8, &Vl[buf][r0][0]);
    }
  };
  float m = -1e30f, lsum = 0.f;
  f32x4 O[4] = {};
  const int nf = qf + 1;
  stage(0, 0);
  __syncthreads();                                   // drain vmcnt + barrier
  for (int kf = 0; kf < nf; ++kf) {
    const int cur = kf & 1;
    if (kf + 1 < nf) stage(cur ^ 1, kf + 1);         // async prefetch next frame
    // K frags from LDS (swizzled read) + swapped QK^T
    f32x4 s[4];
    __builtin_amdgcn_s_setprio(1);
#pragma unroll
    for (int nj = 0; nj < 4; ++nj) {
      const int tr = nj*16 + r15;
      const bf16x8 k0 = *(const bf16x8*)(&Kl[cur][tr][((0*4 + g) ^ (tr & 7)) * 8]);
      const bf16x8 k1 = *(const bf16x8*)(&Kl[cur][tr][((1*4 + g) ^ (tr & 7)) * 8]);
      f32x4 z = {};
      z     = __builtin_amdgcn_mfma_f32_16x16x32_bf16(k0, aq[0], z, 0, 0, 0);
      s[nj] = __builtin_amdgcn_mfma_f32_16x16x32_bf16(k1, aq[1], z, 0, 0, 0);
    }
    __builtin_amdgcn_s_setprio(0);
    // V frags from LDS (independent of softmax; compiler schedules)
    bf16x8 av[2][4];
#pragma unroll
    for (int kc = 0; kc < 2; ++kc)
#pragma unroll
      for (int di = 0; di < 4; ++di) {
        const int dr = di*16 + r15;
        av[kc][di] = *(const bf16x8*)(&Vl[cur][dr][((kc*4 + g) ^ (dr & 7)) * 8]);
      }
    // scalar softmax: in-lane max over 16, 2 shuffles across the q-group
    float pmax = -1e30f;
#pragma unroll
    for (int nj = 0; nj < 4; ++nj)
      pmax = fmaxf(pmax, fmaxf(fmaxf(s[nj][0], s[nj][1]), fmaxf(s[nj][2], s[nj][3])));
    pmax *= SCALE;
    pmax = fmaxf(pmax, __shfl_xor(pmax, 16));
    pmax = fmaxf(pmax, __shfl_xor(pmax, 32));
    if (!__all(pmax - m <= 8.0f)) {                  // defer-max rescale (THR=8)
      const float mn = fmaxf(m, pmax);
      const float fac = __expf(m - mn);
      m = mn; lsum *= fac;
#pragma unroll
      for (int di = 0; di < 4; ++di) {
        O[di][0] *= fac; O[di][1] *= fac; O[di][2] *= fac; O[di][3] *= fac;
      }
    }
    float rs = 0.f;
    short4 pw[4];
#pragma unroll
    for (int nj = 0; nj < 4; ++nj) {
      const float p0 = __expf(s[nj][0]*SCALE - m);
      const float p1 = __expf(s[nj][1]*SCALE - m);
      const float p2 = __expf(s[nj][2]*SCALE - m);
      const float p3 = __expf(s[nj][3]*SCALE - m);
      rs += (p0 + p1) + (p2 + p3);
      union { unsigned u; short2 s2; } c0, c1;
      c0.u = cvt_pk_bf16(p0, p1);
      c1.u = cvt_pk_bf16(p2, p3);
      pw[nj].x = c0.s2.x; pw[nj].y = c0.s2.y;
      pw[nj].z = c1.s2.x; pw[nj].w = c1.s2.y;
    }
    rs += __shfl_xor(rs, 16);
    rs += __shfl_xor(rs, 32);
    lsum += rs;
    // P roundtrip through per-wave LDS (row q = this lane)
#pragma unroll
    for (int nj = 0; nj < 4; ++nj)
      *(short4*)(Prow + nj*16 + g*4) = pw[nj];
    asm volatile("s_waitcnt lgkmcnt(0)" ::: "memory");  // rule #18 fence
    __builtin_amdgcn_sched_barrier(0);
    __builtin_amdgcn_s_setprio(1);
#pragma unroll
    for (int kc = 0; kc < 2; ++kc) {
      const bf16x8 bp = *(const bf16x8*)(Prow + kc*32 + g*8);
#pragma unroll
      for (int di = 0; di < 4; ++di)
        O[di] = __builtin_amdgcn_mfma_f32_16x16x32_bf16(av[kc][di], bp, O[di], 0, 0, 0);
    }
    __builtin_amdgcn_s_setprio(0);
    __syncthreads();                                 // drains prefetch vmcnt + barrier
  }
  const float invl = 1.0f / lsum;
#pragma unroll
  for (int di = 0; di < 4; ++di) {
    uint2 uv;
    uv.x = cvt_pk_bf16(O[di][0]*invl, O[di][1]*invl);
    uv.y = cvt_pk_bf16(O[di][2]*invl, O[di][3]*invl);
    *(uint2*)(aout + (size_t)(tok0 + r15)*768 + h*64 + di*16 + g*4) = uv;
  }
}

extern "C" void kernel_launch(void* const* d_in, const int* in_sizes, int n_in,
                              void* d_out, int out_size, void* d_ws, size_t ws_size,
                              hipStream_t stream)
{
  (void)in_sizes; (void)n_in; (void)out_size; (void)ws_size;
  const float* x_in = (const float*)d_in[0];
  const float* pos  = (const float*)d_in[1];
  const float* ln1w = (const float*)d_in[2];
  const float* ln1b = (const float*)d_in[3];
  const float* wqkv = (const float*)d_in[4];
  const float* wo   = (const float*)d_in[5];
  const float* bo   = (const float*)d_in[6];
  const float* ln2w = (const float*)d_in[7];
  const float* ln2b = (const float*)d_in[8];
  const float* w1   = (const float*)d_in[9];
  const float* b1   = (const float*)d_in[10];
  const float* w2   = (const float*)d_in[11];
  const float* b2   = (const float*)d_in[12];
  const float* lnfw = (const float*)d_in[13];
  const float* lnfb = (const float*)d_in[14];

  size_t off = 0;
  auto carve = [&](size_t bytes) {
    void* p = (char*)d_ws + off;
    off += (bytes + 255) & ~(size_t)255;
    return p;
  };
  short* wqkvT = (short*)carve((size_t)6*2304*768*2);
  short* woT   = (short*)carve((size_t)6*768*768*2);
  short* w1T   = (short*)carve((size_t)6*3072*768*2);
  short* w2T   = (short*)carve((size_t)6*768*3072*2);
  float* x     = (float*)carve((size_t)4096*768*4);
  short* hbuf  = (short*)carve((size_t)4096*768*2);
  short* qkv   = (short*)carve((size_t)4096*2304*2);
  short* vt    = (short*)carve((size_t)48*64*1024*2);
  short* aout  = (short*)carve((size_t)4096*768*2);
  short* mid   = (short*)carve((size_t)4096*3072*2);

  wtrans_k<<<dim3(72,24,6), dim3(32,8), 0, stream>>>(wqkv, wqkvT, 768, 2304);
  wtrans_k<<<dim3(24,24,6), dim3(32,8), 0, stream>>>(wo,   woT,   768, 768);
  wtrans_k<<<dim3(96,24,6), dim3(32,8), 0, stream>>>(w1,   w1T,   768, 3072);
  wtrans_k<<<dim3(24,96,6), dim3(32,8), 0, stream>>>(w2,   w2T,   3072, 768);

  for (int L = 0; L < 6; ++L) {
    if (L == 0)
      ln_k<0,1><<<1024, 256, 0, stream>>>(x_in, pos, ln1w, ln1b, hbuf, x);
    else
      ln_k<0,0><<<1024, 256, 0, stream>>>(x, nullptr, ln1w + L*768, ln1b + L*768, hbuf, nullptr);
    gemm_bt<0,128,1,0><<<dim3(18,32), 256, 0, stream>>>(hbuf, wqkvT + (size_t)L*2304*768,
                                                        4096, 2304, 768, qkv, nullptr, nullptr, vt);
    attn_k<<<dim3(16,12,4), 256, 0, stream>>>(qkv, vt, aout);
    gemm_bt<2,64,2,1><<<dim3(12,32,2), 256, 0, stream>>>(aout, woT + (size_t)L*768*768,
                                                         4096, 768, 768, nullptr, x, bo + L*768, nullptr);
    ln_k<0,0><<<1024, 256, 0, stream>>>(x, nullptr, ln2w + L*768, ln2b + L*768, hbuf, nullptr);
    gemm_bt<1,128,1,0><<<dim3(24,32), 256, 0, stream>>>(hbuf, w1T + (size_t)L*3072*768,
                                                        4096, 3072, 768, mid, nullptr, b1 + L*3072, nullptr);
    gemm_bt<2,64,2,1><<<dim3(12,32,2), 256, 0, stream>>>(mid, w2T + (size_t)L*768*3072,
                                                         4096, 768, 3072, nullptr, x, b2 + L*768, nullptr);
  }
  ln_k<1,0><<<1024, 256, 0, stream>>>(x, nullptr, lnfw, lnfb, d_out, nullptr);
}